// Round 11
// baseline (111.910 us; speedup 1.0000x reference)
//
#include <hip/hip_runtime.h>

#define IN_CH  64
#define OUT_CH 32
#define BLOCK  8

using short8 = __attribute__((ext_vector_type(8))) short;
using f32x4v = __attribute__((ext_vector_type(4))) float;

// ws layout: argmax M*4  (bucket arrays gone -- m-ordered compute)

__global__ void k_prep(int4* __restrict__ argmax4, int n4) {
    int i = blockIdx.x * 256 + threadIdx.x;
    if (i < n4) argmax4[i] = make_int4(-1, -1, -1, -1);
}

// argmax[m] monotone non-decreasing => stale read is a valid lower bound;
// filtered atomicMax is always correct. Dispatch split makes pass-1 results
// visible so pass-2 filters ~all its atomics.
__global__ void k_scatter7(const int* __restrict__ pair, int* __restrict__ argmax, int N) {
    int i = blockIdx.x * 256 + threadIdx.x;
    int q = N / 4 - 1 - i;                    // descending: high-t first
    if (q < 0) return;
    int4 p = ((const int4*)(pair + 7 * N))[q];
    int tb = 7 * N + q * 4;
    if (p.w >= 0 && argmax[p.w] < tb + 3) atomicMax(&argmax[p.w], tb + 3);
    if (p.z >= 0 && argmax[p.z] < tb + 2) atomicMax(&argmax[p.z], tb + 2);
    if (p.y >= 0 && argmax[p.y] < tb + 1) atomicMax(&argmax[p.y], tb + 1);
    if (p.x >= 0 && argmax[p.x] < tb)     atomicMax(&argmax[p.x], tb);
}

__global__ void k_scatter_rest(const int* __restrict__ pair, int* __restrict__ argmax, int N) {
    int i = blockIdx.x * 256 + threadIdx.x;
    if (i >= N / 4) return;
    for (int j = 6; j >= 0; --j) {            // ~87.5% of slots filter on j=7 winner
        int4 p = ((const int4*)(pair + j * N))[i];
        int tb = j * N + i * 4;
        if (p.x >= 0 && argmax[p.x] < tb)     atomicMax(&argmax[p.x], tb);
        if (p.y >= 0 && argmax[p.y] < tb + 1) atomicMax(&argmax[p.y], tb + 1);
        if (p.z >= 0 && argmax[p.z] < tb + 2) atomicMax(&argmax[p.z], tb + 2);
        if (p.w >= 0 && argmax[p.w] < tb + 3) atomicMax(&argmax[p.w], tb + 3);
    }
}

__device__ __forceinline__ unsigned cvt_pk_bf16(float lo, float hi) {
    unsigned r;
    asm("v_cvt_pk_bf16_f32 %0, %1, %2" : "=v"(r) : "v"(lo), "v"(hi));
    return r;
}

__device__ __forceinline__ short8 pack8(float4 a, float4 b) {
    union { unsigned u[4]; short8 s; } p;
    p.u[0] = cvt_pk_bf16(a.x, a.y);
    p.u[1] = cvt_pk_bf16(a.z, a.w);
    p.u[2] = cvt_pk_bf16(b.x, b.y);
    p.u[3] = cvt_pk_bf16(b.z, b.w);
    return p.s;
}

// m-ordered masked MFMA: wave owns 64 consecutive out rows (4x16 subtiles).
// A (16x32): lane row=lane&15, k=(lane>>4)*8+e; B: col=lane&15, k=(lane>>4)*8+e
// C/D: col=lane&15, row=(lane>>4)*4+q   [layout verified by rounds 9/10 passing]
// All 8 j's of B live in VGPRs (128); per j, A is row-masked (jr==j ? a : 0).
// Stores are dense 8KB regions per wave; no bm/bn, no LDS, no shuffles.
__global__ __launch_bounds__(256, 2) void k_compute(
        const float* __restrict__ x, const float* __restrict__ w,
        const int* __restrict__ argmax, float* __restrict__ out,
        int M, int N) {
    const int lane = threadIdx.x & 63;
    const int r16  = lane & 15;
    const int kc   = lane >> 4;
    const int wv   = threadIdx.x >> 6;

    int base = (blockIdx.x * 4 + wv) * 64;
    if (base >= M) return;

    // B fragments for ALL 8 kernel positions: 8 x 2 o-tiles x 2 k-halves
    short8 bf[8][2][2];
#pragma unroll
    for (int j = 0; j < 8; ++j)
#pragma unroll
        for (int ot = 0; ot < 2; ++ot)
#pragma unroll
            for (int kk = 0; kk < 2; ++kk) {
                const float* wp = w + ((ot * 16 + r16) * BLOCK + j) * IN_CH + kk * 32 + kc * 8;
                bf[j][ot][kk] = pack8(*(const float4*)wp, *(const float4*)(wp + 4));
            }

    const int N1 = N, N2 = 2 * N, N4 = 4 * N;

    // all 4 subtile t's up front (coalesced 64B lines), decode branch-free
    int t_[4], j_[4], n_[4];
#pragma unroll
    for (int st = 0; st < 4; ++st) {
        int row = base + st * 16 + r16;
        t_[st] = (row < M) ? argmax[row] : -1;
    }
#pragma unroll
    for (int st = 0; st < 4; ++st) {
        int v = t_[st], j = 0;
        if (v >= N4) { j = 4;  v -= N4; }
        if (v >= N2) { j += 2; v -= N2; }
        if (v >= N1) { j += 1; v -= N1; }
        bool ok = t_[st] >= 0;
        j_[st] = ok ? j : 8;                 // 8 = unmapped sentinel
        n_[st] = ok ? v : 0;
    }

    // x gather, software-pipelined 1 subtile ahead (ping-pong, static idx)
    float4 xs[2][4];
    {
        const float* xp = x + (size_t)n_[0] * IN_CH + kc * 8;
        xs[0][0] = *(const float4*)xp;       xs[0][1] = *(const float4*)(xp + 4);
        xs[0][2] = *(const float4*)(xp + 32); xs[0][3] = *(const float4*)(xp + 36);
    }

#pragma unroll
    for (int st = 0; st < 4; ++st) {
        const int cur = st & 1;
        if (st < 3) {
            const float* xp = x + (size_t)n_[st + 1] * IN_CH + kc * 8;
            xs[cur ^ 1][0] = *(const float4*)xp;        xs[cur ^ 1][1] = *(const float4*)(xp + 4);
            xs[cur ^ 1][2] = *(const float4*)(xp + 32); xs[cur ^ 1][3] = *(const float4*)(xp + 36);
        }

        short8 a0 = pack8(xs[cur][0], xs[cur][1]);   // k 0..31
        short8 a1 = pack8(xs[cur][2], xs[cur][3]);   // k 32..63
        const int jr = j_[st];
        const short8 zz = (short8)0;

        f32x4v acc0 = {0.f, 0.f, 0.f, 0.f};
        f32x4v acc1 = {0.f, 0.f, 0.f, 0.f};
#pragma unroll
        for (int j = 0; j < 8; ++j) {
            bool pj = (jr == j);
            if (__ballot(pj)) {              // skip j's absent from this subtile
                short8 m0 = pj ? a0 : zz;
                short8 m1 = pj ? a1 : zz;
                acc0 = __builtin_amdgcn_mfma_f32_16x16x32_bf16(m0, bf[j][0][0], acc0, 0, 0, 0);
                acc0 = __builtin_amdgcn_mfma_f32_16x16x32_bf16(m1, bf[j][0][1], acc0, 0, 0, 0);
                acc1 = __builtin_amdgcn_mfma_f32_16x16x32_bf16(m0, bf[j][1][0], acc1, 0, 0, 0);
                acc1 = __builtin_amdgcn_mfma_f32_16x16x32_bf16(m1, bf[j][1][1], acc1, 0, 0, 0);
            }
        }

        // dense stores: rows base+st*16+kc*4+q (unmapped rows got all-masked -> 0)
#pragma unroll
        for (int q = 0; q < 4; ++q) {
            int row = base + st * 16 + kc * 4 + q;
            if (row < M) {
                size_t ro = (size_t)row * OUT_CH;
                out[ro + r16]      = acc0[q];
                out[ro + 16 + r16] = acc1[q];
            }
        }
    }
}

extern "C" void kernel_launch(void* const* d_in, const int* in_sizes, int n_in,
                              void* d_out, int out_size, void* d_ws, size_t ws_size,
                              hipStream_t stream) {
    const float* x    = (const float*)d_in[0];
    const float* w    = (const float*)d_in[1];
    const int*   pair = (const int*)d_in[2];
    int N = in_sizes[0] / IN_CH;     // 400000
    int M = out_size / OUT_CH;       // 200000

    int* argmax = (int*)d_ws;

    int n4 = M / 4;                  // M % 4 == 0
    k_prep<<<(n4 + 255) / 256, 256, 0, stream>>>((int4*)argmax, n4);

    int gq = (N / 4 + 255) / 256;
    k_scatter7   <<<gq, 256, 0, stream>>>(pair, argmax, N);   // j=7, high-t first
    k_scatter_rest<<<gq, 256, 0, stream>>>(pair, argmax, N);  // j=6..0, filtered

    int waves  = (M + 63) / 64;
    int blocks = (waves + 3) / 4;
    k_compute<<<blocks, 256, 0, stream>>>(x, w, argmax, (float*)d_out, M, N);
}

// Round 12
// 100.681 us; speedup vs baseline: 1.1115x; 1.1115x over previous
//
#include <hip/hip_runtime.h>

#define IN_CH  64
#define OUT_CH 32
#define BLOCK  8

using short8 = __attribute__((ext_vector_type(8))) short;
using f32x4v = __attribute__((ext_vector_type(4))) float;

// ws layout:
//   [0]        cur[16]  ints (bucket cursors; cur[j] == cnt[j] after k_fill)
//   [256]      argmax   M ints
//   [256+4M]   bm       9*M ints   (bucket j's rows at bm[j*M .. j*M+cnt[j]))
//   [256+40M]  bn       9*M ints

__global__ void k_prep(int4* __restrict__ argmax4, int n4, int* __restrict__ cur) {
    int i = blockIdx.x * 256 + threadIdx.x;
    if (i < 16) cur[i] = 0;
    if (i < n4) argmax4[i] = make_int4(-1, -1, -1, -1);
}

// argmax[m] monotone non-decreasing => stale read is a valid lower bound;
// filtered atomicMax is always correct. Dispatch split makes pass-1 results
// visible so pass-2 filters ~all its atomics.
__global__ void k_scatter7(const int* __restrict__ pair, int* __restrict__ argmax, int N) {
    int i = blockIdx.x * 256 + threadIdx.x;
    int q = N / 4 - 1 - i;                    // descending: high-t first
    if (q < 0) return;
    int4 p = ((const int4*)(pair + 7 * N))[q];
    int tb = 7 * N + q * 4;
    if (p.w >= 0 && argmax[p.w] < tb + 3) atomicMax(&argmax[p.w], tb + 3);
    if (p.z >= 0 && argmax[p.z] < tb + 2) atomicMax(&argmax[p.z], tb + 2);
    if (p.y >= 0 && argmax[p.y] < tb + 1) atomicMax(&argmax[p.y], tb + 1);
    if (p.x >= 0 && argmax[p.x] < tb)     atomicMax(&argmax[p.x], tb);
}

__global__ void k_scatter_rest(const int* __restrict__ pair, int* __restrict__ argmax, int N) {
    int i = blockIdx.x * 256 + threadIdx.x;
    if (i >= N / 4) return;
    for (int j = 6; j >= 0; --j) {            // ~88% of slots filter on j=7 winner
        int4 p = ((const int4*)(pair + j * N))[i];
        int tb = j * N + i * 4;
        if (p.x >= 0 && argmax[p.x] < tb)     atomicMax(&argmax[p.x], tb);
        if (p.y >= 0 && argmax[p.y] < tb + 1) atomicMax(&argmax[p.y], tb + 1);
        if (p.z >= 0 && argmax[p.z] < tb + 2) atomicMax(&argmax[p.z], tb + 2);
        if (p.w >= 0 && argmax[p.w] < tb + 3) atomicMax(&argmax[p.w], tb + 3);
    }
}

// bucket rows by j (fixed regions, per-block LDS hist -> 9 atomics/block)
__global__ void k_fill(const int* __restrict__ argmax, int* __restrict__ cur,
                       int* __restrict__ bm, int* __restrict__ bn, int M, int N) {
    __shared__ int h9[9];
    __shared__ int b9[9];
    if (threadIdx.x < 9) h9[threadIdx.x] = 0;
    __syncthreads();
    int m = blockIdx.x * 256 + threadIdx.x;
    int j = 9, n = 0, lo = 0;
    if (m < M) {
        int t = argmax[m];
        if (t >= 0) { j = (int)((unsigned)t / (unsigned)N); n = t - j * N; }
        else j = 8;
        lo = atomicAdd(&h9[j], 1);
    }
    __syncthreads();
    if (threadIdx.x < 9 && h9[threadIdx.x] > 0)
        b9[threadIdx.x] = atomicAdd(&cur[threadIdx.x], h9[threadIdx.x]);
    __syncthreads();
    if (m < M) {
        int pos = j * M + b9[j] + lo;
        bm[pos] = m;
        bn[pos] = n;
    }
}

__device__ __forceinline__ unsigned cvt_pk_bf16(float lo, float hi) {
    unsigned r;
    asm("v_cvt_pk_bf16_f32 %0, %1, %2" : "=v"(r) : "v"(lo), "v"(hi));
    return r;
}

__device__ __forceinline__ short8 pack8(float4 a, float4 b) {
    union { unsigned u[4]; short8 s; } p;
    p.u[0] = cvt_pk_bf16(a.x, a.y);
    p.u[1] = cvt_pk_bf16(a.z, a.w);
    p.u[2] = cvt_pk_bf16(b.x, b.y);
    p.u[3] = cvt_pk_bf16(b.z, b.w);
    return p.s;
}

// Bucketed MFMA GEMM (j wave-uniform, B in 16 VGPRs), software-pipelined:
// all 4 subtiles' bn/bm loaded upfront (8 independent loads in flight),
// x gathered 1 subtile ahead (ping-pong, static idx under full unroll).
// A (16x32): lane row=lane&15, k=(lane>>4)*8+e; C/D: col=lane&15, row=(lane>>4)*4+q
__global__ __launch_bounds__(256, 4) void k_compute(
        const float* __restrict__ x, const float* __restrict__ w,
        const int* __restrict__ cnt, const int* __restrict__ bm,
        const int* __restrict__ bn, float* __restrict__ out, int M, int N) {
    const int lane = threadIdx.x & 63;
    const int r16  = lane & 15;
    const int kc   = lane >> 4;
    const int wv   = threadIdx.x >> 6;

    // wave -> (bucket j, 64-row tile T); tiles enumerated per bucket
    int T = blockIdx.x * 4 + wv;
    int j = 0, nrows = 0;
    for (; j < 9; ++j) {
        int c  = cnt[j];
        int nt = (c + 63) >> 6;
        if (T < nt) { nrows = min(64, c - T * 64); break; }
        T -= nt;
    }
    if (j >= 9) return;
    int base = j * M + T * 64;
    int jw = (j < 8) ? j : 0;                 // j==8 rows output zeros

    // upfront metadata: bn per lane (clamped) + bm int4 per subtile -- all
    // 8 loads independent and in flight before any use
    int n_[4];
    int4 m4_[4];
#pragma unroll
    for (int st = 0; st < 4; ++st) {
        int lrow = st * 16 + r16;
        n_[st] = bn[base + ((lrow < nrows) ? lrow : 0)];
    }
#pragma unroll
    for (int st = 0; st < 4; ++st)
        m4_[st] = *(const int4*)&bm[base + st * 16 + kc * 4];   // safe: M%64==0

    // B fragments (single j): 2 o-tiles x 2 k-halves, 16 VGPRs, loaded once
    short8 bf[2][2];
#pragma unroll
    for (int ot = 0; ot < 2; ++ot)
#pragma unroll
        for (int kk = 0; kk < 2; ++kk) {
            const float* wp = w + ((ot * 16 + r16) * BLOCK + jw) * IN_CH + kk * 32 + kc * 8;
            bf[ot][kk] = pack8(*(const float4*)wp, *(const float4*)(wp + 4));
        }

    // x pipeline: ping-pong, 1 subtile ahead
    float4 xs[2][4];
    {
        const float* xp = x + (size_t)n_[0] * IN_CH + kc * 8;
        xs[0][0] = *(const float4*)xp;        xs[0][1] = *(const float4*)(xp + 4);
        xs[0][2] = *(const float4*)(xp + 32); xs[0][3] = *(const float4*)(xp + 36);
    }

#pragma unroll
    for (int st = 0; st < 4; ++st) {
        const int cur2 = st & 1;
        if (st < 3 && (st + 1) * 16 < nrows) {
            const float* xp = x + (size_t)n_[st + 1] * IN_CH + kc * 8;
            xs[cur2 ^ 1][0] = *(const float4*)xp;        xs[cur2 ^ 1][1] = *(const float4*)(xp + 4);
            xs[cur2 ^ 1][2] = *(const float4*)(xp + 32); xs[cur2 ^ 1][3] = *(const float4*)(xp + 36);
        }
        if (st * 16 < nrows) {
            short8 a0 = pack8(xs[cur2][0], xs[cur2][1]);   // k 0..31
            short8 a1 = pack8(xs[cur2][2], xs[cur2][3]);   // k 32..63

            f32x4v acc0 = {0.f, 0.f, 0.f, 0.f};
            f32x4v acc1 = {0.f, 0.f, 0.f, 0.f};
            acc0 = __builtin_amdgcn_mfma_f32_16x16x32_bf16(a0, bf[0][0], acc0, 0, 0, 0);
            acc0 = __builtin_amdgcn_mfma_f32_16x16x32_bf16(a1, bf[0][1], acc0, 0, 0, 0);
            acc1 = __builtin_amdgcn_mfma_f32_16x16x32_bf16(a0, bf[1][0], acc1, 0, 0, 0);
            acc1 = __builtin_amdgcn_mfma_f32_16x16x32_bf16(a1, bf[1][1], acc1, 0, 0, 0);

            int ma[4] = {m4_[st].x, m4_[st].y, m4_[st].z, m4_[st].w};
#pragma unroll
            for (int q = 0; q < 4; ++q) {
                int grow = st * 16 + kc * 4 + q;
                if (grow < nrows) {
                    size_t ro = (size_t)ma[q] * OUT_CH;
                    float v0 = (j == 8) ? 0.f : acc0[q];
                    float v1 = (j == 8) ? 0.f : acc1[q];
                    out[ro + r16]      = v0;   // 4x 64B segments per instr
                    out[ro + 16 + r16] = v1;
                }
            }
        }
    }
}

extern "C" void kernel_launch(void* const* d_in, const int* in_sizes, int n_in,
                              void* d_out, int out_size, void* d_ws, size_t ws_size,
                              hipStream_t stream) {
    const float* x    = (const float*)d_in[0];
    const float* w    = (const float*)d_in[1];
    const int*   pair = (const int*)d_in[2];
    int N = in_sizes[0] / IN_CH;     // 400000
    int M = out_size / OUT_CH;       // 200000

    char* ws     = (char*)d_ws;
    int*  cur    = (int*)ws;
    int*  argmax = (int*)(ws + 256);
    int*  bm     = (int*)(ws + 256 + (size_t)M * 4);
    int*  bn     = (int*)(ws + 256 + (size_t)M * 4 + (size_t)9 * M * 4);

    int n4 = M / 4;                  // M % 4 == 0
    k_prep<<<(n4 + 255) / 256, 256, 0, stream>>>((int4*)argmax, n4, cur);

    int gq = (N / 4 + 255) / 256;
    k_scatter7    <<<gq, 256, 0, stream>>>(pair, argmax, N);   // j=7, high-t first
    k_scatter_rest<<<gq, 256, 0, stream>>>(pair, argmax, N);   // j=6..0, filtered

    k_fill<<<(M + 255) / 256, 256, 0, stream>>>(argmax, cur, bm, bn, M, N);

    int maxtiles = (M + 63) / 64 + 9;                 // worst case across buckets
    int blocks   = (maxtiles + 3) / 4;                // 4 waves / 256-thread block
    k_compute<<<blocks, 256, 0, stream>>>(x, w, cur, bm, bn, (float*)d_out, M, N);
}